// Round 5
// baseline (242.151 us; speedup 1.0000x reference)
//
#include <hip/hip_runtime.h>

#define NCACHE 384

__device__ __forceinline__ unsigned int sortable_bits(float f) {
    unsigned int u = __float_as_uint(f);
    return (u & 0x80000000u) ? ~u : (u | 0x80000000u);
}

// 256 threads = 4 waves; wave w handles b = blockIdx.x*4 + w entirely.
__global__ __launch_bounds__(256) void fused_kernel(
    const float*  __restrict__ cache,        // (384,5)
    const float*  __restrict__ refdirs,      // (B,3)
    const float*  __restrict__ normal,       // (B,3)
    const float4* __restrict__ samp_rays4,   // B*96 float4
    const float4* __restrict__ samp_mip4,    // B*32 float4
    float* __restrict__ out, int B)
{
#pragma clang fp contract(off)
    __shared__ float sdx[NCACHE], sdy[NCACHE], sdz[NCACHE], smip[NCACHE];
    __shared__ unsigned int bitmap[4][12];

    const int tid  = threadIdx.x;
    const int wave = tid >> 6;
    const int lane = tid & 63;
    const int b    = blockIdx.x * 4 + wave;

    // Stage cache into LDS (cooperative, once per block)
    for (int m = tid; m < NCACHE; m += 256) {
        sdx[m]  = cache[m * 5 + 0];
        sdy[m]  = cache[m * 5 + 1];
        sdz[m]  = cache[m * 5 + 2];
        smip[m] = cache[m * 5 + 3];
    }
    if (tid < 48) (&bitmap[0][0])[tid] = 0u;

    const float nx = normal[b * 3 + 0], ny = normal[b * 3 + 1], nz = normal[b * 3 + 2];
    const float rx = refdirs[b * 3 + 0], ry = refdirs[b * 3 + 1], rz = refdirs[b * 3 + 2];

    __syncthreads();

    // Per-lane stable keys for j = 64c + lane, c = 0..5 (all 384 keys in regs).
    // FMA left-chains, bit-exact vs reference; -0.0 canonicalized to +0.0.
    unsigned long long k[6];
#pragma unroll
    for (int c = 0; c < 6; ++c) {
        const int j = c * 64 + lane;
        float dx = sdx[j], dy = sdy[j], dz = sdz[j];
        float hemi = __builtin_fmaf(nz, dz, __builtin_fmaf(ny, dy, nx * dx));
        float sim  = __builtin_fmaf(rz, dz, __builtin_fmaf(ry, dy, rx * dx));
        float val  = (hemi > 0.0f) ? -sim : 0.0f;
        val = val + 0.0f;
        k[c] = ((unsigned long long)sortable_bits(val) << 32) | (unsigned int)j;
    }

    // Stable rank of m = 0..127 among all 384 keys, ballot-counted:
    // per m: broadcast key_m (readlane), 6x v_cmp_lt_u64 -> 64-bit mask,
    // popcount on the SCALAR pipe. r stays uniform; select into lane m&63.
    int r0 = 0, r1 = 0;
#pragma unroll
    for (int c = 0; c < 2; ++c) {
        const unsigned int klo = (unsigned int)k[c];
        const unsigned int khi = (unsigned int)(k[c] >> 32);
#pragma unroll 4
        for (int l = 0; l < 64; ++l) {
            const unsigned int mlo = (unsigned int)__builtin_amdgcn_readlane((int)klo, l);
            const unsigned int mhi = (unsigned int)__builtin_amdgcn_readlane((int)khi, l);
            const unsigned long long km = ((unsigned long long)mhi << 32) | mlo;
            int rank = 0;
#pragma unroll
            for (int c2 = 0; c2 < 6; ++c2)
                rank += __popcll(__ballot(k[c2] < km));
            if (c == 0) r0 = (lane == l) ? rank : r0;
            else        r1 = (lane == l) ? rank : r1;
        }
    }

    // Ranks are distinct in [0,384). Output slot = #{selected ranks < r}.
    atomicOr(&bitmap[wave][r0 >> 5], 1u << (r0 & 31));
    atomicOr(&bitmap[wave][r1 >> 5], 1u << (r1 & 31));
    __syncthreads();

    float* out_rays = out;
    float* out_mip  = out + (size_t)B * 768;

    {
        const int wi = r0 >> 5;
        int s = __popc(bitmap[wave][wi] & ((1u << (r0 & 31)) - 1u));
        for (int w = 0; w < wi; ++w) s += __popc(bitmap[wave][w]);
        const size_t rb = (size_t)b * 768 + 384 + (size_t)s * 3;
        out_rays[rb + 0] = sdx[r0];
        out_rays[rb + 1] = sdy[r0];
        out_rays[rb + 2] = sdz[r0];
        out_mip[(size_t)b * 256 + 128 + s] = smip[r0];
    }
    {
        const int wi = r1 >> 5;
        int s = __popc(bitmap[wave][wi] & ((1u << (r1 & 31)) - 1u));
        for (int w = 0; w < wi; ++w) s += __popc(bitmap[wave][w]);
        const size_t rb = (size_t)b * 768 + 384 + (size_t)s * 3;
        out_rays[rb + 0] = sdx[r1];
        out_rays[rb + 1] = sdy[r1];
        out_rays[rb + 2] = sdz[r1];
        out_mip[(size_t)b * 256 + 128 + s] = smip[r1];
    }

    // Fused pass-through copies for this block's 4 b values:
    // rays: 96 f4 per b -> out f4 row b*192 (+0..95); mip: 32 f4 per b -> mip f4 row b*64 (+0..31)
    float4* out4     = (float4*)out;
    float4* out_mip4 = (float4*)(out + (size_t)B * 768);
    const int b0 = blockIdx.x * 4;
#pragma unroll
    for (int i = tid; i < 512; i += 256) {
        const int bw  = i >> 7;
        const int off = i & 127;
        const int bb  = b0 + bw;
        if (off < 96) {
            out4[(size_t)bb * 192 + off] = samp_rays4[(size_t)bb * 96 + off];
        } else {
            out_mip4[(size_t)bb * 64 + (off - 96)] = samp_mip4[(size_t)bb * 32 + (off - 96)];
        }
    }
}

extern "C" void kernel_launch(void* const* d_in, const int* in_sizes, int n_in,
                              void* d_out, int out_size, void* d_ws, size_t ws_size,
                              hipStream_t stream) {
    const float* cache       = (const float*)d_in[0];
    const float* refdirs     = (const float*)d_in[1];
    const float* normal      = (const float*)d_in[2];
    const float* samp_rays   = (const float*)d_in[3];
    const float* samp_mipval = (const float*)d_in[4];
    float* out = (float*)d_out;

    const int B = in_sizes[1] / 3;  // 65536

    fused_kernel<<<B / 4, 256, 0, stream>>>(cache, refdirs, normal,
                                            (const float4*)samp_rays,
                                            (const float4*)samp_mipval,
                                            out, B);
}

// Round 6
// 206.583 us; speedup vs baseline: 1.1722x; 1.1722x over previous
//
#include <hip/hip_runtime.h>

#define NCACHE 384

__device__ __forceinline__ unsigned int sortable_bits(float f) {
    unsigned int u = __float_as_uint(f);
    return (u & 0x80000000u) ? ~u : (u | 0x80000000u);
}

struct __align__(16) u64x2 { unsigned long long x, y; };

// 256 threads = 4 waves; wave w handles b = blockIdx.x*4 + w entirely.
__global__ __launch_bounds__(256) void fused_kernel(
    const float*  __restrict__ cache,        // (384,5)
    const float*  __restrict__ refdirs,      // (B,3)
    const float*  __restrict__ normal,       // (B,3)
    const float4* __restrict__ samp_rays4,   // B*96 float4
    const float4* __restrict__ samp_mip4,    // B*32 float4
    float* __restrict__ out, int B)
{
#pragma clang fp contract(off)
    __shared__ float sdx[NCACHE], sdy[NCACHE], sdz[NCACHE], smip[NCACHE];
    __shared__ __align__(16) unsigned long long keys[4][NCACHE];
    __shared__ unsigned int bitmap[4][12];

    const int tid  = threadIdx.x;
    const int wave = tid >> 6;
    const int lane = tid & 63;
    const int b    = blockIdx.x * 4 + wave;

    // ---- Early-issue the pass-through copy loads (hide HBM under rank loop).
    // 512 f4 items per block: item i: bb = b0 + (i>>7), off = i&127;
    // off<96 -> rays f4 (bb*96+off), else mip f4 (bb*32+off-96).
    const int b0 = blockIdx.x * 4;
    const int i0 = tid, i1 = tid + 256;
    const int bb0 = b0 + (i0 >> 7), off0 = i0 & 127;
    const int bb1 = b0 + (i1 >> 7), off1 = i1 & 127;
    const float4 c0 = (off0 < 96) ? samp_rays4[(size_t)bb0 * 96 + off0]
                                  : samp_mip4[(size_t)bb0 * 32 + (off0 - 96)];
    const float4 c1 = (off1 < 96) ? samp_rays4[(size_t)bb1 * 96 + off1]
                                  : samp_mip4[(size_t)bb1 * 32 + (off1 - 96)];

    // Stage cache into LDS (cooperative, once per block)
    for (int m = tid; m < NCACHE; m += 256) {
        sdx[m]  = cache[m * 5 + 0];
        sdy[m]  = cache[m * 5 + 1];
        sdz[m]  = cache[m * 5 + 2];
        smip[m] = cache[m * 5 + 3];
    }
    if (tid < 48) (&bitmap[0][0])[tid] = 0u;

    const float nx = normal[b * 3 + 0], ny = normal[b * 3 + 1], nz = normal[b * 3 + 2];
    const float rx = refdirs[b * 3 + 0], ry = refdirs[b * 3 + 1], rz = refdirs[b * 3 + 2];

    __syncthreads();

    // Scores -> stable keys (FMA left-chains, bit-exact vs reference; -0.0 -> +0.0)
    for (int m = lane; m < NCACHE; m += 64) {
        float dx = sdx[m], dy = sdy[m], dz = sdz[m];
        float hemi = __builtin_fmaf(nz, dz, __builtin_fmaf(ny, dy, nx * dx));
        float sim  = __builtin_fmaf(rz, dz, __builtin_fmaf(ry, dy, rx * dx));
        float val  = (hemi > 0.0f) ? -sim : 0.0f;
        val = val + 0.0f;
        keys[wave][m] = ((unsigned long long)sortable_bits(val) << 32) | (unsigned int)m;
    }
    __syncthreads();

    // Stable ranks for m0=lane, m1=lane+64 among all 384 keys.
    // Inner body in inline asm: v_cmp_lt_u64 + v_addc_co_u32 = 2 VALU per pair
    // (compiler lowering of r += (a<b) costs 3+). Loads stay in C++ for
    // scheduling/addressing.
    const unsigned long long k0 = keys[wave][lane];
    const unsigned long long k1 = keys[wave][lane + 64];
    const u64x2* kp = (const u64x2*)&keys[wave][0];
    unsigned int r0 = 0, r1 = 0;
#pragma unroll 8
    for (int j = 0; j < NCACHE / 2; ++j) {
        u64x2 kk = kp[j];
        asm("v_cmp_lt_u64 vcc, %[ax], %[ka]\n\t"
            "v_addc_co_u32 %[r0], vcc, 0, %[r0], vcc\n\t"
            "v_cmp_lt_u64 vcc, %[ay], %[ka]\n\t"
            "v_addc_co_u32 %[r0], vcc, 0, %[r0], vcc\n\t"
            "v_cmp_lt_u64 vcc, %[ax], %[kb]\n\t"
            "v_addc_co_u32 %[r1], vcc, 0, %[r1], vcc\n\t"
            "v_cmp_lt_u64 vcc, %[ay], %[kb]\n\t"
            "v_addc_co_u32 %[r1], vcc, 0, %[r1], vcc"
            : [r0] "+v"(r0), [r1] "+v"(r1)
            : [ax] "v"(kk.x), [ay] "v"(kk.y), [ka] "v"(k0), [kb] "v"(k1)
            : "vcc");
    }

    // Ranks are distinct in [0,384). Output slot = #{selected ranks < r}.
    atomicOr(&bitmap[wave][r0 >> 5], 1u << (r0 & 31));
    atomicOr(&bitmap[wave][r1 >> 5], 1u << (r1 & 31));
    __syncthreads();

    float* out_rays = out;
    float* out_mip  = out + (size_t)B * 768;

    {
        const int wi = (int)r0 >> 5;
        int s = __popc(bitmap[wave][wi] & ((1u << (r0 & 31)) - 1u));
        for (int w = 0; w < wi; ++w) s += __popc(bitmap[wave][w]);
        const size_t rb = (size_t)b * 768 + 384 + (size_t)s * 3;
        out_rays[rb + 0] = sdx[r0];
        out_rays[rb + 1] = sdy[r0];
        out_rays[rb + 2] = sdz[r0];
        out_mip[(size_t)b * 256 + 128 + s] = smip[r0];
    }
    {
        const int wi = (int)r1 >> 5;
        int s = __popc(bitmap[wave][wi] & ((1u << (r1 & 31)) - 1u));
        for (int w = 0; w < wi; ++w) s += __popc(bitmap[wave][w]);
        const size_t rb = (size_t)b * 768 + 384 + (size_t)s * 3;
        out_rays[rb + 0] = sdx[r1];
        out_rays[rb + 1] = sdy[r1];
        out_rays[rb + 2] = sdz[r1];
        out_mip[(size_t)b * 256 + 128 + s] = smip[r1];
    }

    // Pass-through copy stores (loads issued at kernel entry).
    float4* out4     = (float4*)out;
    float4* out_mip4 = (float4*)(out + (size_t)B * 768);
    if (off0 < 96) out4[(size_t)bb0 * 192 + off0] = c0;
    else           out_mip4[(size_t)bb0 * 64 + (off0 - 96)] = c0;
    if (off1 < 96) out4[(size_t)bb1 * 192 + off1] = c1;
    else           out_mip4[(size_t)bb1 * 64 + (off1 - 96)] = c1;
}

extern "C" void kernel_launch(void* const* d_in, const int* in_sizes, int n_in,
                              void* d_out, int out_size, void* d_ws, size_t ws_size,
                              hipStream_t stream) {
    const float* cache       = (const float*)d_in[0];
    const float* refdirs     = (const float*)d_in[1];
    const float* normal      = (const float*)d_in[2];
    const float* samp_rays   = (const float*)d_in[3];
    const float* samp_mipval = (const float*)d_in[4];
    float* out = (float*)d_out;

    const int B = in_sizes[1] / 3;  // 65536

    fused_kernel<<<B / 4, 256, 0, stream>>>(cache, refdirs, normal,
                                            (const float4*)samp_rays,
                                            (const float4*)samp_mipval,
                                            out, B);
}